// Round 5
// baseline (373.063 us; speedup 1.0000x reference)
//
#include <hip/hip_runtime.h>
#include <hip/hip_bf16.h>

#define HID 128
#define IN_DIM 16

typedef short bf16x8 __attribute__((ext_vector_type(8)));
typedef float f32x4 __attribute__((ext_vector_type(4)));

// ---------- bf16 helpers (RNE) ----------
__device__ __forceinline__ unsigned short f2bf(float f) {
    unsigned int u = __float_as_uint(f);
    unsigned int r = (u + 0x7FFFu + ((u >> 16) & 1u)) >> 16;
    return (unsigned short)r;
}
__device__ __forceinline__ float bf2f(unsigned short u) {
    return __uint_as_float(((unsigned int)u) << 16);
}

// ---------------- zero words (indeg [int] + pooled [float]) ----------------
__global__ __launch_bounds__(256) void k_zero_words(unsigned int* p, int n) {
    int i = blockIdx.x * blockDim.x + threadIdx.x;
    if (i < n) p[i] = 0u;
}

__global__ __launch_bounds__(256) void k_count(const int* __restrict__ dst, int* indeg, int E) {
    int e = blockIdx.x * blockDim.x + threadIdx.x;
    if (e < E) atomicAdd(&indeg[dst[e]], 1);
}

// ---------------- 2-level exclusive scan over indeg ----------------
__global__ __launch_bounds__(256) void k_scan1(const int* __restrict__ indeg, int* __restrict__ offs,
                                               int* __restrict__ blocksum, int N) {
    __shared__ int sdata[256];
    int base = blockIdx.x * 1024 + threadIdx.x * 4;
    int v0 = (base + 0 < N) ? indeg[base + 0] : 0;
    int v1 = (base + 1 < N) ? indeg[base + 1] : 0;
    int v2 = (base + 2 < N) ? indeg[base + 2] : 0;
    int v3 = (base + 3 < N) ? indeg[base + 3] : 0;
    int s = v0 + v1 + v2 + v3;
    sdata[threadIdx.x] = s;
    __syncthreads();
    for (int off = 1; off < 256; off <<= 1) {
        int t = (threadIdx.x >= off) ? sdata[threadIdx.x - off] : 0;
        __syncthreads();
        sdata[threadIdx.x] += t;
        __syncthreads();
    }
    int excl = sdata[threadIdx.x] - s;
    if (base + 0 < N) offs[base + 0] = excl;  excl += v0;
    if (base + 1 < N) offs[base + 1] = excl;  excl += v1;
    if (base + 2 < N) offs[base + 2] = excl;  excl += v2;
    if (base + 3 < N) offs[base + 3] = excl;
    if (threadIdx.x == 255) blocksum[blockIdx.x] = sdata[255];
}

__global__ void k_scan2(int* blocksum, int nblk) {
    if (blockIdx.x == 0 && threadIdx.x == 0) {
        int acc = 0;
        for (int i = 0; i < nblk; ++i) { int t = blocksum[i]; blocksum[i] = acc; acc += t; }
    }
}

// scan finalize + cursor init + dinv (fused)
__global__ __launch_bounds__(256) void k_scan3(int* __restrict__ offs, int* __restrict__ cursor,
                                               const int* __restrict__ blocksum,
                                               const int* __restrict__ indeg,
                                               float* __restrict__ dinv, int N) {
    int i = blockIdx.x * blockDim.x + threadIdx.x;
    if (i < N) {
        int o = offs[i] + blocksum[i >> 10];
        offs[i] = o;
        cursor[i] = o;
        dinv[i] = rsqrtf(1.0f + (float)indeg[i]);
    }
}

__global__ __launch_bounds__(256) void k_fill(const int* __restrict__ src, const int* __restrict__ dst,
                                              int* __restrict__ cursor, int* __restrict__ csr, int E) {
    int e = blockIdx.x * blockDim.x + threadIdx.x;
    if (e < E) {
        int pos = atomicAdd(&cursor[dst[e]], 1);
        csr[pos] = src[e];
    }
}

// ---------------- per-graph counts: batch sorted -> binary search ----------------
__global__ void k_cnt_bs(const int* __restrict__ batch, float* __restrict__ cnt, int N, int G) {
    int g = blockIdx.x * blockDim.x + threadIdx.x;
    if (g >= G) return;
    int lo = 0, hi = N;
    while (lo < hi) { int mid = (lo + hi) >> 1; if (batch[mid] < g) lo = mid + 1; else hi = mid; }
    int start = lo;
    lo = 0; hi = N;
    while (lo < hi) { int mid = (lo + hi) >> 1; if (batch[mid] <= g) lo = mid + 1; else hi = mid; }
    cnt[g] = (float)(lo - start);
}

// ---------------- prep: xs16[i] = bf16(dinv_i * x_i)  [N,16] ----------------
__global__ __launch_bounds__(256) void k_prep_x(const float* __restrict__ x,
                                                const float* __restrict__ dinv,
                                                unsigned short* __restrict__ xs16, int N) {
    int t = blockIdx.x * blockDim.x + threadIdx.x;
    if (t >= N * 4) return;
    int node = t >> 2, q = t & 3;
    float di = dinv[node];
    float4 v = *reinterpret_cast<const float4*>(x + (size_t)node * IN_DIM + q * 4);
    ushort4 o;
    o.x = f2bf(di * v.x); o.y = f2bf(di * v.y);
    o.z = f2bf(di * v.z); o.w = f2bf(di * v.w);
    *reinterpret_cast<ushort4*>(xs16 + (size_t)node * IN_DIM + q * 4) = o;
}

// ---------------- gather16: y[i] = xs16[i] + sum_{j in N(i)} xs16[j]   (4 thr/node) ----------------
__global__ __launch_bounds__(256) void k_gather16(const unsigned short* __restrict__ xs16,
                                                  const int* __restrict__ offs,
                                                  const int* __restrict__ indeg,
                                                  const int* __restrict__ csr,
                                                  float* __restrict__ y, int N) {
    int t = blockIdx.x * 256 + threadIdx.x;
    int node = t >> 2;
    if (node >= N) return;
    int c = (t & 3) * 4;
    int base = offs[node], deg = indeg[node];
    ushort4 ow = *reinterpret_cast<const ushort4*>(xs16 + (size_t)node * IN_DIM + c);
    float ax = bf2f(ow.x), ay = bf2f(ow.y), az = bf2f(ow.z), aw = bf2f(ow.w);
    int j = 0;
    for (; j + 4 <= deg; j += 4) {
        int s0 = csr[base + j + 0], s1 = csr[base + j + 1];
        int s2 = csr[base + j + 2], s3 = csr[base + j + 3];
        ushort4 v0 = *reinterpret_cast<const ushort4*>(xs16 + (size_t)s0 * IN_DIM + c);
        ushort4 v1 = *reinterpret_cast<const ushort4*>(xs16 + (size_t)s1 * IN_DIM + c);
        ushort4 v2 = *reinterpret_cast<const ushort4*>(xs16 + (size_t)s2 * IN_DIM + c);
        ushort4 v3 = *reinterpret_cast<const ushort4*>(xs16 + (size_t)s3 * IN_DIM + c);
        ax += (bf2f(v0.x) + bf2f(v1.x)) + (bf2f(v2.x) + bf2f(v3.x));
        ay += (bf2f(v0.y) + bf2f(v1.y)) + (bf2f(v2.y) + bf2f(v3.y));
        az += (bf2f(v0.z) + bf2f(v1.z)) + (bf2f(v2.z) + bf2f(v3.z));
        aw += (bf2f(v0.w) + bf2f(v1.w)) + (bf2f(v2.w) + bf2f(v3.w));
    }
    for (; j < deg; ++j) {
        int s = csr[base + j];
        ushort4 v = *reinterpret_cast<const ushort4*>(xs16 + (size_t)s * IN_DIM + c);
        ax += bf2f(v.x); ay += bf2f(v.y); az += bf2f(v.z); aw += bf2f(v.w);
    }
    *reinterpret_cast<float4*>(y + (size_t)node * IN_DIM + c) = make_float4(ax, ay, az, aw);
}

// ---------------- GEMM1b: h1[i] = bf16(relu(dinv_i*(y[i]@W1) + b1)), y [N,16] ----------------
__global__ __launch_bounds__(256) void k_gemm1b(const float* __restrict__ y,
                                                const float* __restrict__ W1,
                                                const float* __restrict__ dinv,
                                                const float* __restrict__ b1,
                                                unsigned short* __restrict__ out, int N) {
    __shared__ float Ws[IN_DIM * HID];   // 8 KB
    __shared__ float xs[8][IN_DIM];      // 512 B
    int nb = blockIdx.x * 8;
    for (int i = threadIdx.x * 4; i < IN_DIM * HID; i += 256 * 4)
        *reinterpret_cast<float4*>(&Ws[i]) = *reinterpret_cast<const float4*>(&W1[i]);
    int nrows = min(8, N - nb);
    if (threadIdx.x < 32) {
        int r = threadIdx.x >> 2, c = (threadIdx.x & 3) * 4;
        if (r < nrows)
            *reinterpret_cast<float4*>(&xs[r][c]) =
                *reinterpret_cast<const float4*>(&y[(size_t)(nb + r) * IN_DIM + c]);
    }
    __syncthreads();
    int f = threadIdx.x & 127;
    int g = threadIdx.x >> 7;
    float bb = b1[f];
    for (int r = g; r < nrows; r += 2) {
        int node = nb + r;
        float acc = 0.f;
        #pragma unroll
        for (int k = 0; k < IN_DIM; ++k) acc += xs[r][k] * Ws[k * HID + f];
        out[(size_t)node * HID + f] = f2bf(fmaxf(dinv[node] * acc + bb, 0.f));
    }
}

// ---------------- W2 -> bf16 transposed: W2T[n][k] = bf16(W2[k][n]) ----------------
__global__ __launch_bounds__(256) void k_w2t(const float* __restrict__ W2,
                                             unsigned short* __restrict__ W2T) {
    int t = blockIdx.x * 256 + threadIdx.x;   // 16384 total
    int n = t >> 7, k = t & 127;
    W2T[t] = f2bf(W2[(size_t)k * HID + n]);
}

// ---------------- GEMM2 MFMA: h2[i] = bf16(dinv_i * (h1[i] @ W2)) ----------------
// A = h1 bf16 [Npad,128]; B^T = W2T bf16 [128 n][128 k]; 4 waves * 16 rows = 64 rows/block.
// mfma_f32_16x16x32_bf16: A row=lane&15, k=(lane>>4)*8+j ; B col=lane&15, same k ;
// D col=lane&15, row=(lane>>4)*4+reg   [verified m89 layout]
__global__ __launch_bounds__(256) void k_gemm2_mfma(const unsigned short* __restrict__ h1,
                                                    const unsigned short* __restrict__ W2T,
                                                    const float* __restrict__ dinv,
                                                    unsigned short* __restrict__ h2, int N) {
    int wave = threadIdx.x >> 6;
    int lane = threadIdx.x & 63;
    int R = blockIdx.x * 64 + wave * 16;
    int lr = lane & 15;
    int lk = (lane >> 4) * 8;
    f32x4 acc[8] = {};
    const unsigned short* arow = h1 + (size_t)(R + lr) * HID;
    #pragma unroll
    for (int kk = 0; kk < 4; ++kk) {
        bf16x8 a = *reinterpret_cast<const bf16x8*>(arow + kk * 32 + lk);
        #pragma unroll
        for (int cf = 0; cf < 8; ++cf) {
            bf16x8 b = *reinterpret_cast<const bf16x8*>(W2T + (size_t)(cf * 16 + lr) * HID + kk * 32 + lk);
            acc[cf] = __builtin_amdgcn_mfma_f32_16x16x32_bf16(a, b, acc[cf], 0, 0, 0);
        }
    }
    int r0 = (lane >> 4) * 4;
    #pragma unroll
    for (int r = 0; r < 4; ++r) {
        int node = R + r0 + r;
        if (node < N) {
            float di = dinv[node];
            #pragma unroll
            for (int cf = 0; cf < 8; ++cf)
                h2[(size_t)node * HID + cf * 16 + lr] = f2bf(di * acc[cf][r]);
        }
    }
}

// ---------------- conv2 gather (bf16 rows, full wave per node) + mean-pool ----------------
__global__ __launch_bounds__(256) void k_conv2_gather_pool(const unsigned short* __restrict__ h,
                                                           const int* __restrict__ offs,
                                                           const int* __restrict__ indeg,
                                                           const int* __restrict__ csr,
                                                           const float* __restrict__ dinv,
                                                           const float* __restrict__ bias,
                                                           const int* __restrict__ batch,
                                                           float* __restrict__ pooled, int N) {
    __shared__ float pool_s[HID];
    int nb = blockIdx.x * 4;
    int t = threadIdx.x;
    int node = nb + (t >> 6);
    int c = (t & 63) * 2;
    bool valid = node < N;
    float v0 = 0.f, v1 = 0.f;
    if (valid) {
        int base = offs[node], deg = indeg[node];
        float ax = 0.f, ay = 0.f;
        int j = 0;
        for (; j + 4 <= deg; j += 4) {
            int s0 = csr[base + j + 0], s1 = csr[base + j + 1];
            int s2 = csr[base + j + 2], s3 = csr[base + j + 3];
            ushort2 a0 = *reinterpret_cast<const ushort2*>(h + (size_t)s0 * HID + c);
            ushort2 a1 = *reinterpret_cast<const ushort2*>(h + (size_t)s1 * HID + c);
            ushort2 a2 = *reinterpret_cast<const ushort2*>(h + (size_t)s2 * HID + c);
            ushort2 a3 = *reinterpret_cast<const ushort2*>(h + (size_t)s3 * HID + c);
            ax += (bf2f(a0.x) + bf2f(a1.x)) + (bf2f(a2.x) + bf2f(a3.x));
            ay += (bf2f(a0.y) + bf2f(a1.y)) + (bf2f(a2.y) + bf2f(a3.y));
        }
        for (; j < deg; ++j) {
            int s = csr[base + j];
            ushort2 a = *reinterpret_cast<const ushort2*>(h + (size_t)s * HID + c);
            ax += bf2f(a.x); ay += bf2f(a.y);
        }
        ushort2 ow = *reinterpret_cast<const ushort2*>(h + (size_t)node * HID + c);
        float di = dinv[node];
        v0 = fmaxf(di * (ax + bf2f(ow.x)) + bias[c + 0], 0.f);
        v1 = fmaxf(di * (ay + bf2f(ow.y)) + bias[c + 1], 0.f);
    }
    int gfirst = batch[min(nb, N - 1)];
    int glast  = batch[min(nb + 3, N - 1)];
    if (gfirst == glast) {
        if (t < HID) pool_s[t] = 0.f;
        __syncthreads();
        if (valid) {
            atomicAdd(&pool_s[c + 0], v0);
            atomicAdd(&pool_s[c + 1], v1);
        }
        __syncthreads();
        if (t < 32) {
            float4 v = *reinterpret_cast<float4*>(&pool_s[t * 4]);
            float* p = pooled + (size_t)gfirst * HID + t * 4;
            atomicAdd(p + 0, v.x);
            atomicAdd(p + 1, v.y);
            atomicAdd(p + 2, v.z);
            atomicAdd(p + 3, v.w);
        }
    } else if (valid) {
        float* p = pooled + (size_t)batch[node] * HID + c;
        atomicAdd(p + 0, v0);
        atomicAdd(p + 1, v1);
    }
}

// ---------------- final FC ----------------
__global__ __launch_bounds__(256) void k_fc(const float* __restrict__ pooled,
                                            const float* __restrict__ cnt,
                                            const float* __restrict__ Wfc,
                                            const float* __restrict__ bfc,
                                            float* __restrict__ out, int G, int O) {
    int t = blockIdx.x * blockDim.x + threadIdx.x;
    if (t >= G * O) return;
    int g = t / O, o = t % O;
    float acc = 0.f;
    for (int k = 0; k < HID; ++k) acc += pooled[(size_t)g * HID + k] * Wfc[(size_t)k * O + o];
    out[t] = acc / fmaxf(cnt[g], 1.f) + bfc[o];
}

extern "C" void kernel_launch(void* const* d_in, const int* in_sizes, int n_in,
                              void* d_out, int out_size, void* d_ws, size_t ws_size,
                              hipStream_t stream) {
    const float* x     = (const float*)d_in[0];
    const int*   ei    = (const int*)d_in[1];
    const int*   batch = (const int*)d_in[2];
    const float* W1    = (const float*)d_in[3];
    const float* b1    = (const float*)d_in[4];
    const float* W2    = (const float*)d_in[5];
    const float* b2    = (const float*)d_in[6];
    const float* Wfc   = (const float*)d_in[7];
    const float* bfc   = (const float*)d_in[8];
    float* out = (float*)d_out;

    const int E = in_sizes[1] / 2;
    const int N = in_sizes[2];
    const int O = in_sizes[8];              // 16
    const int G = out_size / O;             // 64
    const int Npad = ((N + 63) / 64) * 64;  // MFMA row padding

    const int* src = ei;
    const int* dst = ei + E;

    // workspace layout
    char* ws = (char*)d_ws;
    int*   indeg  = (int*)ws;                        ws += sizeof(int) * N;
    float* pooled = (float*)ws;                      ws += sizeof(float) * G * HID;
    float* dinv   = (float*)ws;                      ws += sizeof(float) * N;
    int*   offs   = (int*)ws;                        ws += sizeof(int) * N;
    int*   cursor = (int*)ws;                        ws += sizeof(int) * N;
    int*   csr    = (int*)ws;                        ws += sizeof(int) * E;
    int*   blocksum = (int*)ws;                      ws += sizeof(int) * 256;
    float* cnt    = (float*)ws;                      ws += sizeof(float) * G;
    float* y      = (float*)ws;                      ws += sizeof(float) * (size_t)N * IN_DIM;
    unsigned short* xs16 = (unsigned short*)ws;      ws += sizeof(unsigned short) * (size_t)N * IN_DIM;
    unsigned short* w2t  = (unsigned short*)ws;      ws += sizeof(unsigned short) * (size_t)HID * HID;
    unsigned short* h1bf = (unsigned short*)ws;      ws += sizeof(unsigned short) * (size_t)Npad * HID;
    unsigned short* h2bf = (unsigned short*)ws;      ws += sizeof(unsigned short) * (size_t)N * HID;

    const int BS = 256;
    const int NBLK_SCAN = (N + 1023) / 1024;

    // zero indeg + pooled (adjacent)
    k_zero_words<<<(N + G * HID + BS - 1) / BS, BS, 0, stream>>>((unsigned int*)indeg, N + G * HID);
    // CSR build
    k_count<<<(E + BS - 1) / BS, BS, 0, stream>>>(dst, indeg, E);
    k_scan1<<<NBLK_SCAN, BS, 0, stream>>>(indeg, offs, blocksum, N);
    k_scan2<<<1, 64, 0, stream>>>(blocksum, NBLK_SCAN);
    k_scan3<<<(N + BS - 1) / BS, BS, 0, stream>>>(offs, cursor, blocksum, indeg, dinv, N);
    k_fill<<<(E + BS - 1) / BS, BS, 0, stream>>>(src, dst, cursor, csr, E);

    // per-graph counts (batch sorted)
    k_cnt_bs<<<1, 64, 0, stream>>>(batch, cnt, N, G);

    // W2 -> bf16 transposed (for MFMA B-fragments)
    k_w2t<<<(HID * HID) / BS, BS, 0, stream>>>(W2, w2t);

    // conv1: xs16 = bf16(dinv*x); y = gather16; h1bf = bf16(relu(dinv*(y@W1)+b1))
    k_prep_x<<<(N * 4 + BS - 1) / BS, BS, 0, stream>>>(x, dinv, xs16, N);
    k_gather16<<<(N * 4 + BS - 1) / BS, BS, 0, stream>>>(xs16, offs, indeg, csr, y, N);
    k_gemm1b<<<(N + 7) / 8, BS, 0, stream>>>(y, W1, dinv, b1, h1bf, N);

    // conv2: h2bf = bf16(dinv*(h1@W2)) via MFMA; gather + epilogue + pool
    k_gemm2_mfma<<<Npad / 64, BS, 0, stream>>>(h1bf, w2t, dinv, h2bf, N);
    k_conv2_gather_pool<<<(N + 3) / 4, BS, 0, stream>>>(h2bf, offs, indeg, csr, dinv, b2, batch, pooled, N);

    // FC head
    k_fc<<<(G * O + BS - 1) / BS, BS, 0, stream>>>(pooled, cnt, Wfc, bfc, out, G, O);
}

// Round 6
// 274.244 us; speedup vs baseline: 1.3603x; 1.3603x over previous
//
#include <hip/hip_runtime.h>
#include <hip/hip_bf16.h>

#define HID 128
#define IN_DIM 16

typedef short bf16x8 __attribute__((ext_vector_type(8)));
typedef float f32x4 __attribute__((ext_vector_type(4)));

// ---------- bf16 helpers (RNE) ----------
__device__ __forceinline__ unsigned short f2bf(float f) {
    unsigned int u = __float_as_uint(f);
    unsigned int r = (u + 0x7FFFu + ((u >> 16) & 1u)) >> 16;
    return (unsigned short)r;
}
__device__ __forceinline__ float bf2f(unsigned short u) {
    return __uint_as_float(((unsigned int)u) << 16);
}

// ---------------- zero words (indeg [int] + pooled [float], adjacent) ----------------
__global__ __launch_bounds__(256) void k_zero_words(unsigned int* p, int n) {
    int i = blockIdx.x * blockDim.x + threadIdx.x;
    if (i < n) p[i] = 0u;
}

__global__ __launch_bounds__(256) void k_count(const int* __restrict__ dst, int* indeg, int E) {
    int e = blockIdx.x * blockDim.x + threadIdx.x;
    if (e < E) atomicAdd(&indeg[dst[e]], 1);
}

// ---------------- 2-level exclusive scan over indeg ----------------
__global__ __launch_bounds__(256) void k_scan1(const int* __restrict__ indeg, int* __restrict__ offs,
                                               int* __restrict__ blocksum, int N) {
    __shared__ int sdata[256];
    int base = blockIdx.x * 1024 + threadIdx.x * 4;
    int v0 = (base + 0 < N) ? indeg[base + 0] : 0;
    int v1 = (base + 1 < N) ? indeg[base + 1] : 0;
    int v2 = (base + 2 < N) ? indeg[base + 2] : 0;
    int v3 = (base + 3 < N) ? indeg[base + 3] : 0;
    int s = v0 + v1 + v2 + v3;
    sdata[threadIdx.x] = s;
    __syncthreads();
    for (int off = 1; off < 256; off <<= 1) {
        int t = (threadIdx.x >= off) ? sdata[threadIdx.x - off] : 0;
        __syncthreads();
        sdata[threadIdx.x] += t;
        __syncthreads();
    }
    int excl = sdata[threadIdx.x] - s;
    if (base + 0 < N) offs[base + 0] = excl;  excl += v0;
    if (base + 1 < N) offs[base + 1] = excl;  excl += v1;
    if (base + 2 < N) offs[base + 2] = excl;  excl += v2;
    if (base + 3 < N) offs[base + 3] = excl;
    if (threadIdx.x == 255) blocksum[blockIdx.x] = sdata[255];
}

// wave-parallel exclusive scan of blocksum (nblk <= 64 fast path)
__global__ void k_scan2(int* blocksum, int nblk) {
    int lane = threadIdx.x;
    if (nblk <= 64) {
        int orig = (lane < nblk) ? blocksum[lane] : 0;
        int v = orig;
        #pragma unroll
        for (int off = 1; off < 64; off <<= 1) {
            int t = __shfl_up(v, off, 64);
            if (lane >= off) v += t;
        }
        if (lane < nblk) blocksum[lane] = v - orig;
    } else if (lane == 0) {
        int acc = 0;
        for (int i = 0; i < nblk; ++i) { int t = blocksum[i]; blocksum[i] = acc; acc += t; }
    }
}

// scan finalize + cursor init + dinv + xs16 = bf16(dinv*x)  (fused)
__global__ __launch_bounds__(256) void k_scan3(int* __restrict__ offs, int* __restrict__ cursor,
                                               const int* __restrict__ blocksum,
                                               const int* __restrict__ indeg,
                                               float* __restrict__ dinv,
                                               const float* __restrict__ x,
                                               unsigned short* __restrict__ xs16, int N) {
    int i = blockIdx.x * blockDim.x + threadIdx.x;
    if (i >= N) return;
    int o = offs[i] + blocksum[i >> 10];
    offs[i] = o;
    cursor[i] = o;
    float di = rsqrtf(1.0f + (float)indeg[i]);
    dinv[i] = di;
    #pragma unroll
    for (int q = 0; q < 4; ++q) {
        float4 v = *reinterpret_cast<const float4*>(x + (size_t)i * IN_DIM + q * 4);
        ushort4 o4;
        o4.x = f2bf(di * v.x); o4.y = f2bf(di * v.y);
        o4.z = f2bf(di * v.z); o4.w = f2bf(di * v.w);
        *reinterpret_cast<ushort4*>(xs16 + (size_t)i * IN_DIM + q * 4) = o4;
    }
}

__global__ __launch_bounds__(256) void k_fill(const int* __restrict__ src, const int* __restrict__ dst,
                                              int* __restrict__ cursor, int* __restrict__ csr, int E) {
    int e = blockIdx.x * blockDim.x + threadIdx.x;
    if (e < E) {
        int pos = atomicAdd(&cursor[dst[e]], 1);
        csr[pos] = src[e];
    }
}

// ---------------- aux: per-graph counts (block 0) + W2 transpose->bf16 (blocks 1..64) ----------------
__global__ __launch_bounds__(256) void k_aux(const int* __restrict__ batch, float* __restrict__ cnt,
                                             const float* __restrict__ W2,
                                             unsigned short* __restrict__ W2T, int N, int G) {
    if (blockIdx.x == 0) {
        int g = threadIdx.x;
        if (g >= G) return;
        int lo = 0, hi = N;
        while (lo < hi) { int mid = (lo + hi) >> 1; if (batch[mid] < g) lo = mid + 1; else hi = mid; }
        int start = lo;
        lo = 0; hi = N;
        while (lo < hi) { int mid = (lo + hi) >> 1; if (batch[mid] <= g) lo = mid + 1; else hi = mid; }
        cnt[g] = (float)(lo - start);
    } else {
        int t = (blockIdx.x - 1) * 256 + threadIdx.x;   // 0..16383
        int n = t >> 7, k = t & 127;
        W2T[t] = f2bf(W2[(size_t)k * HID + n]);
    }
}

// ---------------- gather16: y[i] = xs16[i] + sum_{j in N(i)} xs16[j]   (4 thr/node, unroll 8) ----------------
__global__ __launch_bounds__(256) void k_gather16(const unsigned short* __restrict__ xs16,
                                                  const int* __restrict__ offs,
                                                  const int* __restrict__ indeg,
                                                  const int* __restrict__ csr,
                                                  float* __restrict__ y, int N) {
    int t = blockIdx.x * 256 + threadIdx.x;
    int node = t >> 2;
    if (node >= N) return;
    int c = (t & 3) * 4;
    int base = offs[node], deg = indeg[node];
    ushort4 ow = *reinterpret_cast<const ushort4*>(xs16 + (size_t)node * IN_DIM + c);
    float ax = bf2f(ow.x), ay = bf2f(ow.y), az = bf2f(ow.z), aw = bf2f(ow.w);
    int j = 0;
    for (; j + 8 <= deg; j += 8) {
        int sI[8];
        #pragma unroll
        for (int u = 0; u < 8; ++u) sI[u] = csr[base + j + u];
        ushort4 v[8];
        #pragma unroll
        for (int u = 0; u < 8; ++u)
            v[u] = *reinterpret_cast<const ushort4*>(xs16 + (size_t)sI[u] * IN_DIM + c);
        #pragma unroll
        for (int u = 0; u < 8; ++u) {
            ax += bf2f(v[u].x); ay += bf2f(v[u].y);
            az += bf2f(v[u].z); aw += bf2f(v[u].w);
        }
    }
    for (; j < deg; ++j) {
        int s = csr[base + j];
        ushort4 v = *reinterpret_cast<const ushort4*>(xs16 + (size_t)s * IN_DIM + c);
        ax += bf2f(v.x); ay += bf2f(v.y); az += bf2f(v.z); aw += bf2f(v.w);
    }
    *reinterpret_cast<float4*>(y + (size_t)node * IN_DIM + c) = make_float4(ax, ay, az, aw);
}

// ---------------- GEMM1b: h1p[i] = bf16(dinv_i * relu(dinv_i*(y[i]@W1) + b1)) ----------------
__global__ __launch_bounds__(256) void k_gemm1b(const float* __restrict__ y,
                                                const float* __restrict__ W1,
                                                const float* __restrict__ dinv,
                                                const float* __restrict__ b1,
                                                unsigned short* __restrict__ out, int N) {
    __shared__ float Ws[IN_DIM * HID];   // 8 KB
    __shared__ float xs[8][IN_DIM];      // 512 B
    int nb = blockIdx.x * 8;
    for (int i = threadIdx.x * 4; i < IN_DIM * HID; i += 256 * 4)
        *reinterpret_cast<float4*>(&Ws[i]) = *reinterpret_cast<const float4*>(&W1[i]);
    int nrows = min(8, N - nb);
    if (threadIdx.x < 32) {
        int r = threadIdx.x >> 2, c = (threadIdx.x & 3) * 4;
        if (r < nrows)
            *reinterpret_cast<float4*>(&xs[r][c]) =
                *reinterpret_cast<const float4*>(&y[(size_t)(nb + r) * IN_DIM + c]);
    }
    __syncthreads();
    int f = threadIdx.x & 127;
    int g = threadIdx.x >> 7;
    float bb = b1[f];
    for (int r = g; r < nrows; r += 2) {
        int node = nb + r;
        float acc = 0.f;
        #pragma unroll
        for (int k = 0; k < IN_DIM; ++k) acc += xs[r][k] * Ws[k * HID + f];
        float di = dinv[node];
        out[(size_t)node * HID + f] = f2bf(di * fmaxf(di * acc + bb, 0.f));
    }
}

// ---------------- gather_z: z[i] = h1p[i] + sum_{j in N(i)} h1p[j]  (32 thr/node, ushort4, unroll 8) ----------------
__global__ __launch_bounds__(256) void k_gather_z(const unsigned short* __restrict__ h1p,
                                                  const int* __restrict__ offs,
                                                  const int* __restrict__ indeg,
                                                  const int* __restrict__ csr,
                                                  unsigned short* __restrict__ z, int N) {
    int t = blockIdx.x * 256 + threadIdx.x;
    int node = t >> 5;
    if (node >= N) return;
    int c = (t & 31) * 4;
    int base = offs[node], deg = indeg[node];
    ushort4 ow = *reinterpret_cast<const ushort4*>(h1p + (size_t)node * HID + c);
    float ax = bf2f(ow.x), ay = bf2f(ow.y), az = bf2f(ow.z), aw = bf2f(ow.w);
    int j = 0;
    for (; j + 8 <= deg; j += 8) {
        int sI[8];
        #pragma unroll
        for (int u = 0; u < 8; ++u) sI[u] = csr[base + j + u];
        ushort4 v[8];
        #pragma unroll
        for (int u = 0; u < 8; ++u)
            v[u] = *reinterpret_cast<const ushort4*>(h1p + (size_t)sI[u] * HID + c);
        #pragma unroll
        for (int u = 0; u < 8; ++u) {
            ax += bf2f(v[u].x); ay += bf2f(v[u].y);
            az += bf2f(v[u].z); aw += bf2f(v[u].w);
        }
    }
    for (; j + 4 <= deg; j += 4) {
        int s0 = csr[base + j + 0], s1 = csr[base + j + 1];
        int s2 = csr[base + j + 2], s3 = csr[base + j + 3];
        ushort4 v0 = *reinterpret_cast<const ushort4*>(h1p + (size_t)s0 * HID + c);
        ushort4 v1 = *reinterpret_cast<const ushort4*>(h1p + (size_t)s1 * HID + c);
        ushort4 v2 = *reinterpret_cast<const ushort4*>(h1p + (size_t)s2 * HID + c);
        ushort4 v3 = *reinterpret_cast<const ushort4*>(h1p + (size_t)s3 * HID + c);
        ax += (bf2f(v0.x) + bf2f(v1.x)) + (bf2f(v2.x) + bf2f(v3.x));
        ay += (bf2f(v0.y) + bf2f(v1.y)) + (bf2f(v2.y) + bf2f(v3.y));
        az += (bf2f(v0.z) + bf2f(v1.z)) + (bf2f(v2.z) + bf2f(v3.z));
        aw += (bf2f(v0.w) + bf2f(v1.w)) + (bf2f(v2.w) + bf2f(v3.w));
    }
    for (; j < deg; ++j) {
        int s = csr[base + j];
        ushort4 v = *reinterpret_cast<const ushort4*>(h1p + (size_t)s * HID + c);
        ax += bf2f(v.x); ay += bf2f(v.y); az += bf2f(v.z); aw += bf2f(v.w);
    }
    ushort4 o;
    o.x = f2bf(ax); o.y = f2bf(ay); o.z = f2bf(az); o.w = f2bf(aw);
    *reinterpret_cast<ushort4*>(z + (size_t)node * HID + c) = o;
}

// ---------------- GEMM2-MFMA + fused mean-pool ----------------
// out2_i = relu(dinv_i*(z_i @ W2) + b2); pooled[batch[i]] += out2_i.
// A = z bf16 [Npad,128]; B^T = W2T [128n][128k]; 4 waves * 16 rows = 64 rows/block.
// mfma_f32_16x16x32_bf16: A row=lane&15,k=(lane>>4)*8+j; D col=lane&15,row=(lane>>4)*4+reg [m89]
__global__ __launch_bounds__(256) void k_gemm2_pool(const unsigned short* __restrict__ z,
                                                    const unsigned short* __restrict__ W2T,
                                                    const float* __restrict__ dinv,
                                                    const float* __restrict__ b2,
                                                    const int* __restrict__ batch,
                                                    float* __restrict__ pooled, int N) {
    __shared__ float pool_s[HID];
    int wave = threadIdx.x >> 6;
    int lane = threadIdx.x & 63;
    int R = blockIdx.x * 64 + wave * 16;
    int lr = lane & 15;
    int lk = (lane >> 4) * 8;
    f32x4 acc[8] = {};
    const unsigned short* arow = z + (size_t)(R + lr) * HID;
    #pragma unroll
    for (int kk = 0; kk < 4; ++kk) {
        bf16x8 a = *reinterpret_cast<const bf16x8*>(arow + kk * 32 + lk);
        #pragma unroll
        for (int cf = 0; cf < 8; ++cf) {
            bf16x8 b = *reinterpret_cast<const bf16x8*>(W2T + (size_t)(cf * 16 + lr) * HID + kk * 32 + lk);
            acc[cf] = __builtin_amdgcn_mfma_f32_16x16x32_bf16(a, b, acc[cf], 0, 0, 0);
        }
    }
    int r0 = (lane >> 4) * 4;
    float di[4];
    int nd[4];
    #pragma unroll
    for (int r = 0; r < 4; ++r) {
        nd[r] = R + r0 + r;
        di[r] = (nd[r] < N) ? dinv[nd[r]] : 0.f;
    }
    int R0 = blockIdx.x * 64;
    int gid0 = batch[min(R0, N - 1)];
    bool single = (R0 + 63 < N) && (batch[R0 + 63] == gid0);
    if (single) {
        if (threadIdx.x < HID) pool_s[threadIdx.x] = 0.f;
        __syncthreads();
        #pragma unroll
        for (int cf = 0; cf < 8; ++cf) {
            float bb = b2[cf * 16 + lr];
            float sc = 0.f;
            #pragma unroll
            for (int r = 0; r < 4; ++r)
                sc += fmaxf(di[r] * acc[cf][r] + bb, 0.f);
            sc += __shfl_xor(sc, 16);
            sc += __shfl_xor(sc, 32);
            if (lane < 16) atomicAdd(&pool_s[cf * 16 + lr], sc);
        }
        __syncthreads();
        if (threadIdx.x < HID)
            atomicAdd(&pooled[(size_t)gid0 * HID + threadIdx.x], pool_s[threadIdx.x]);
    } else {
        #pragma unroll
        for (int r = 0; r < 4; ++r) {
            if (nd[r] < N) {
                int bi = batch[nd[r]];
                #pragma unroll
                for (int cf = 0; cf < 8; ++cf) {
                    float v = fmaxf(di[r] * acc[cf][r] + b2[cf * 16 + lr], 0.f);
                    atomicAdd(&pooled[(size_t)bi * HID + cf * 16 + lr], v);
                }
            }
        }
    }
}

// ---------------- final FC ----------------
__global__ __launch_bounds__(256) void k_fc(const float* __restrict__ pooled,
                                            const float* __restrict__ cnt,
                                            const float* __restrict__ Wfc,
                                            const float* __restrict__ bfc,
                                            float* __restrict__ out, int G, int O) {
    int t = blockIdx.x * blockDim.x + threadIdx.x;
    if (t >= G * O) return;
    int g = t / O, o = t % O;
    float acc = 0.f;
    for (int k = 0; k < HID; ++k) acc += pooled[(size_t)g * HID + k] * Wfc[(size_t)k * O + o];
    out[t] = acc / fmaxf(cnt[g], 1.f) + bfc[o];
}

extern "C" void kernel_launch(void* const* d_in, const int* in_sizes, int n_in,
                              void* d_out, int out_size, void* d_ws, size_t ws_size,
                              hipStream_t stream) {
    const float* x     = (const float*)d_in[0];
    const int*   ei    = (const int*)d_in[1];
    const int*   batch = (const int*)d_in[2];
    const float* W1    = (const float*)d_in[3];
    const float* b1    = (const float*)d_in[4];
    const float* W2    = (const float*)d_in[5];
    const float* b2    = (const float*)d_in[6];
    const float* Wfc   = (const float*)d_in[7];
    const float* bfc   = (const float*)d_in[8];
    float* out = (float*)d_out;

    const int E = in_sizes[1] / 2;
    const int N = in_sizes[2];
    const int O = in_sizes[8];              // 16
    const int G = out_size / O;             // 64
    const int Npad = ((N + 63) / 64) * 64;

    const int* src = ei;
    const int* dst = ei + E;

    // workspace layout (all segments 16B-multiples for N=50000/E=800000)
    char* ws = (char*)d_ws;
    int*   indeg  = (int*)ws;                        ws += sizeof(int) * N;
    float* pooled = (float*)ws;                      ws += sizeof(float) * G * HID;
    float* dinv   = (float*)ws;                      ws += sizeof(float) * N;
    int*   offs   = (int*)ws;                        ws += sizeof(int) * N;
    int*   cursor = (int*)ws;                        ws += sizeof(int) * N;
    int*   csr    = (int*)ws;                        ws += sizeof(int) * E;
    int*   blocksum = (int*)ws;                      ws += sizeof(int) * 256;
    float* cnt    = (float*)ws;                      ws += sizeof(float) * G;
    float* y      = (float*)ws;                      ws += sizeof(float) * (size_t)N * IN_DIM;
    unsigned short* xs16 = (unsigned short*)ws;      ws += sizeof(unsigned short) * (size_t)N * IN_DIM;
    unsigned short* w2t  = (unsigned short*)ws;      ws += sizeof(unsigned short) * (size_t)HID * HID;
    unsigned short* h1p  = (unsigned short*)ws;      ws += sizeof(unsigned short) * (size_t)Npad * HID;
    unsigned short* z    = (unsigned short*)ws;      ws += sizeof(unsigned short) * (size_t)Npad * HID;

    const int BS = 256;
    const int NBLK_SCAN = (N + 1023) / 1024;

    k_zero_words<<<(N + G * HID + BS - 1) / BS, BS, 0, stream>>>((unsigned int*)indeg, N + G * HID);
    k_count<<<(E + BS - 1) / BS, BS, 0, stream>>>(dst, indeg, E);
    k_scan1<<<NBLK_SCAN, BS, 0, stream>>>(indeg, offs, blocksum, N);
    k_scan2<<<1, 64, 0, stream>>>(blocksum, NBLK_SCAN);
    k_scan3<<<(N + BS - 1) / BS, BS, 0, stream>>>(offs, cursor, blocksum, indeg, dinv, x, xs16, N);
    k_fill<<<(E + BS - 1) / BS, BS, 0, stream>>>(src, dst, cursor, csr, E);
    k_aux<<<1 + (HID * HID) / BS, BS, 0, stream>>>(batch, cnt, W2, w2t, N, G);

    // conv1
    k_gather16<<<(N * 4 + BS - 1) / BS, BS, 0, stream>>>(xs16, offs, indeg, csr, y, N);
    k_gemm1b<<<(N + 7) / 8, BS, 0, stream>>>(y, W1, dinv, b1, h1p, N);

    // conv2 (gather-then-GEMM, pool fused)
    k_gather_z<<<(N * 32 + BS - 1) / BS, BS, 0, stream>>>(h1p, offs, indeg, csr, z, N);
    k_gemm2_pool<<<Npad / 64, BS, 0, stream>>>(z, w2t, dinv, b2, batch, pooled, N);

    // FC head
    k_fc<<<(G * O + BS - 1) / BS, BS, 0, stream>>>(pooled, cnt, Wfc, bfc, out, G, O);
}